// Round 4
// baseline (254.393 us; speedup 1.0000x reference)
//
#include <hip/hip_runtime.h>
#include <math.h>

// Non-explicit FP stays separate mul/add; explicit fma models the reference's
// contraction (XLA CPU AllowFPOpFusion::Fast). NUMERICS FROZEN SINCE R3:
// absmax 1.117587e-08. All structural changes are bit-identical per-element,
// HW-VALIDATED (identical absmax) across R7/R9:
//  - A2/A4 mirrors are BITWISE equal: term k of A2[j][i] is
//    (-A[k][j])*(-A[i][k]) == A[i][k]*A[k][j] exactly, same k-order; A4 same
//    argument over bitwise-symmetric A2. A6=A4*A2 NOT bitwise symmetric.
//  - U fold into P=U+V / Q=V-U per element: identical chains, no reorder.
//  - swap restricted to LIVE Q column-pairs (lanes j<k hold dead L after
//    step j's update and are never read again).
//  - getrf trailing update as pk pairs from c0=k>>1: live lanes (j>k) get the
//    identical fma(-lik, Q[k][j], Q[i][j]); corrupted lanes (j<=k) are dead L
//    storage, with lik read into a register first.
//  - gram upper+x2 weighting: bitwise-symmetric gram (same products, same
//    k-order); only final f32 sum order changes — established invisible.
// REGISTER STRATEGY (hard lessons R4/R6/R7/R9):
//  - NO occupancy-forcing attribute: waves_per_eu(5) clamped to 48 VGPR and
//    spilled 1.2 GB (605us). (256,3)/(256,2) also spilled.
//  - Occupancy HALVES above 128 VGPR (m69 steps at 64/128/256): R9's 136-VGPR
//    build ran at 10.4% occupancy vs 18.5% at 128 — 124 vs 88 us. STAY <=128.
//  - R9's named gather temps (rkq/rkp/tq/tp = 32 VGPRs held across the swap
//    i-loop) were the register delta vs R0's in-place swap. Swap must be the
//    in-place progressive form: same cndmask count, 2 transient f2 temps.
#pragma clang fp contract(off)

typedef float f2 __attribute__((ext_vector_type(2)));

static __device__ __forceinline__ f2 sp(float x) { f2 r; r.x = x; r.y = x; return r; }
static __device__ __forceinline__ f2 sel2(bool d, f2 a, f2 b) {
  f2 r; r.x = d ? a.x : b.x; r.y = d ? a.y : b.y; return r;
}
#define FMA2(A, B, C) __builtin_elementwise_fma((A), (B), (C))

// element access into row-major f2-packed 8x8: m[i*4 + (j>>1)] lane (j&1)
#define EL(m, i, j) (m[(i)*4 + ((j) >> 1)][(j) & 1])

// Full 8x8 matmul, fmaf k-chain, f2-paired over j. Used by the rare squaring
// path only. Bitwise == R5's scalar mm8 (full 8-term chains, first term mul).
__device__ __forceinline__ void mm8p(const f2* __restrict__ A,
                                     const f2* __restrict__ B,
                                     f2* __restrict__ C) {
  #pragma unroll
  for (int i = 0; i < 8; ++i) {
    #pragma unroll
    for (int c = 0; c < 4; ++c) {
      f2 s = sp(EL(A, i, 0)) * B[0*4 + c];
      #pragma unroll
      for (int k = 1; k < 8; ++k)
        s = FMA2(sp(EL(A, i, k)), B[k*4 + c], s);
      C[i*4 + c] = s;
    }
  }
}

// One thread per 8x8 block, 256-thread workgroups, NO min-waves bound:
// (256,1) leaves the allocator free; R0/R5 measured 128 VGPR, zero spill,
// on this dataflow shape (peak live = aa+W+V+P = 256 floats).
__global__ __launch_bounds__(256, 1)
void triality_kernel(const float* __restrict__ in, double* __restrict__ acc)
{
  const int t = blockIdx.x * 256 + threadIdx.x;
  const float4* src = (const float4*)(in + (size_t)t * 64);

  float p[64];
  #pragma unroll
  for (int i = 0; i < 16; ++i) {
    float4 q4 = src[i];
    p[4*i+0] = q4.x; p[4*i+1] = q4.y; p[4*i+2] = q4.z; p[4*i+3] = q4.w;
  }

  // A = 0.5*(P - P^T), all 64 entries each with its own sub+mul (R5 exact;
  // diag = +0 exactly).
  f2 aa[32];
  #pragma unroll
  for (int i = 0; i < 8; ++i)
    #pragma unroll
    for (int j = 0; j < 8; ++j)
      EL(aa, i, j) = 0.5f * (p[i*8+j] - p[j*8+i]);

  // 1-norm: per column j, cs = sum_i |a[i][j]| in ascending i (incl. diag +0),
  // then running max — identical op order to R5.
  float l1 = 0.0f;
  #pragma unroll
  for (int j = 0; j < 8; ++j) {
    float cs = 0.0f;
    #pragma unroll
    for (int i = 0; i < 8; ++i) cs = cs + fabsf(EL(aa, i, j));
    l1 = fmaxf(l1, cs);
  }

  // n_squarings = max(0, floor(log2(A_L1 / 3.925724783138660)))
  float fl = floorf(log2f(l1 / 3.925724783138660f));
  int ns = (fl > 0.0f) ? (int)fl : 0;
  if (ns > 0) {
    f2 sc = sp(exp2f((float)(-ns)));   // exact power of two
    #pragma unroll
    for (int e = 0; e < 32; ++e) aa[e] = aa[e] * sc;   // pk_mul, per-lane exact
  }

  // A2 = A*A (bitwise symmetric): compute f2 pairs with 2c+1 >= i, mirror the
  // 12 fully-lower pairs (mirror values proven bit-identical, header; HW-
  // validated R7/R9). Full 8-term fmaf chains, j-paired — chains == R5.
  f2 a2[32];
  #pragma unroll
  for (int i = 0; i < 8; ++i)
    #pragma unroll
    for (int c = 0; c < 4; ++c) {
      if (2*c + 1 >= i) {
        f2 s = sp(EL(aa, i, 0)) * aa[0*4 + c];
        #pragma unroll
        for (int k = 1; k < 8; ++k)
          s = FMA2(sp(EL(aa, i, k)), aa[k*4 + c], s);
        a2[i*4 + c] = s;
      }
    }
  #pragma unroll
  for (int i = 0; i < 8; ++i)
    #pragma unroll
    for (int c = 0; c < 4; ++c)
      if (2*c + 1 < i) {
        EL(a2, i, 2*c)     = EL(a2, 2*c,     i);
        EL(a2, i, 2*c + 1) = EL(a2, 2*c + 1, i);
      }

  // A4 = A2*A2 (bitwise symmetric, same argument over symmetric A2): compute
  // upper pairs, mirror the rest. Chains identical to R5/R6's full compute.
  f2 a4[32];
  #pragma unroll
  for (int i = 0; i < 8; ++i)
    #pragma unroll
    for (int c = 0; c < 4; ++c) {
      if (2*c + 1 >= i) {
        f2 s = sp(EL(a2, i, 0)) * a2[0*4 + c];
        #pragma unroll
        for (int k = 1; k < 8; ++k)
          s = FMA2(sp(EL(a2, i, k)), a2[k*4 + c], s);
        a4[i*4 + c] = s;
      }
    }
  #pragma unroll
  for (int i = 0; i < 8; ++i)
    #pragma unroll
    for (int c = 0; c < 4; ++c)
      if (2*c + 1 < i) {
        EL(a4, i, 2*c)     = EL(a4, 2*c,     i);
        EL(a4, i, 2*c + 1) = EL(a4, 2*c + 1, i);
      }

  // A6 = A4*A2 (full — not bitwise symmetric)
  f2 w6[32];
  #pragma unroll
  for (int i = 0; i < 8; ++i)
    #pragma unroll
    for (int c = 0; c < 4; ++c) {
      f2 s = sp(EL(a4, i, 0)) * a2[0*4 + c];
      #pragma unroll
      for (int k = 1; k < 8; ++k)
        s = FMA2(sp(EL(a4, i, k)), a2[k*4 + c], s);
      w6[i*4 + c] = s;
    }

  // XLA backend-fused polynomial combine (validated R3), j-paired, in place:
  //   W = fma(277200, A2, fma(1512, A4, A6)) + diag(8648640)   -> w6
  //   V = fma(1995840, A2, fma(56, A6, 25200*A4)) + diag(17297280) -> vv
  f2 vv[32];
  #pragma unroll
  for (int e = 0; e < 32; ++e) {
    f2 x6 = w6[e], x4 = a4[e], x2 = a2[e];
    f2 w = FMA2(sp(1512.0f), x4, x6);
    w = FMA2(sp(277200.0f), x2, w);
    f2 v = FMA2(sp(56.0f), x6, sp(25200.0f) * x4);
    v = FMA2(sp(1995840.0f), x2, v);
    w6[e] = w; vv[e] = v;
  }
  #pragma unroll
  for (int i = 0; i < 8; ++i) {   // diagonal adds (scalar halves)
    EL(w6, i, i) = EL(w6, i, i) + 8648640.0f;
    EL(vv, i, i) = EL(vv, i, i) + 17297280.0f;
  }

  // U = A @ W (full chains; k==i term is fmaf(+-0,y,s)==s — R5-equivalent),
  // folded per element into P = U + V (new array) and Q = V − U (in place of
  // V). Identical chains/values to the separate-loop form (HW-validated).
  f2 uu[32];
  #pragma unroll
  for (int i = 0; i < 8; ++i)
    #pragma unroll
    for (int c = 0; c < 4; ++c) {
      f2 s = sp(EL(aa, i, 0)) * w6[0*4 + c];
      #pragma unroll
      for (int k = 1; k < 8; ++k)
        s = FMA2(sp(EL(aa, i, k)), w6[k*4 + c], s);
      f2 V = vv[i*4 + c];
      uu[i*4 + c] = s + V;   // P = U + V
      vv[i*4 + c] = V - s;   // Q = V - U
    }
  f2* P = uu;
  f2* Q = vv;

  // ---- fused augmented elimination on [Q|P]: getrf(Q) + laswp(P) +
  // unit-lower trsm, interleaved per step k (bit-identical to the separate
  // passes). Swap is IN-PLACE progressive (R0 form — no named temp block;
  // d true at most once so row k ends up correct), restricted to LIVE Q
  // column-pairs (c >= k>>1) + all P columns.
  #pragma unroll
  for (int k = 0; k < 8; ++k) {
    float amax = fabsf(EL(Q, k, k)); int jp = k;
    #pragma unroll
    for (int i = k + 1; i < 8; ++i) {
      float av = fabsf(EL(Q, i, k));
      if (av > amax) { amax = av; jp = i; }   // first max, like isamax
    }
    const int c0 = k >> 1;
    #pragma unroll
    for (int i = k + 1; i < 8; ++i) {
      bool d = (jp == i);
      #pragma unroll
      for (int c = c0; c < 4; ++c) {
        f2 qk = Q[k*4 + c], qi = Q[i*4 + c];
        Q[k*4 + c] = sel2(d, qi, qk);
        Q[i*4 + c] = sel2(d, qk, qi);
      }
      #pragma unroll
      for (int c = 0; c < 4; ++c) {
        f2 pk_ = P[k*4 + c], pi = P[i*4 + c];
        P[k*4 + c] = sel2(d, pi, pk_);
        P[i*4 + c] = sel2(d, pk_, pi);
      }
    }

    // pivot-column scale: direct IEEE divide (validated R3)
    float dk = EL(Q, k, k);
    #pragma unroll
    for (int i = k + 1; i < 8; ++i) EL(Q, i, k) = EL(Q, i, k) / dk;
    // trailing updates: Q as pk pairs over live columns (lik read first;
    // corrupted lanes j<=k are dead L storage) + P row-axpy (pk).
    #pragma unroll
    for (int i = k + 1; i < 8; ++i) {
      float lik = EL(Q, i, k);
      f2 nl = sp(-lik);
      #pragma unroll
      for (int c = c0; c < 4; ++c)
        Q[i*4 + c] = FMA2(nl, Q[k*4 + c], Q[i*4 + c]);
      #pragma unroll
      for (int c = 0; c < 4; ++c)
        P[i*4 + c] = FMA2(nl, P[k*4 + c], P[i*4 + c]);
    }
  }

  // strsm: non-unit upper, k descending, IEEE f32 divide per element
  #pragma unroll
  for (int k = 7; k >= 0; --k) {
    float dk = EL(Q, k, k);
    #pragma unroll
    for (int j = 0; j < 8; ++j) EL(P, k, j) = EL(P, k, j) / dk;
    #pragma unroll
    for (int i = 0; i < k; ++i) {
      f2 nu = sp(-EL(Q, i, k));
      #pragma unroll
      for (int c = 0; c < 4; ++c)
        P[i*4 + c] = FMA2(nu, P[k*4 + c], P[i*4 + c]);
    }
  }

  // repeated squaring (ns in {0,1} statistically)
  for (int sq = 0; sq < ns; ++sq) {
    f2 t2[32];
    mm8p(P, P, t2);
    #pragma unroll
    for (int e = 0; e < 32; ++e) P[e] = t2[e];
  }

  // gram = R^T R - I: bitwise symmetric -> compute pairs with 2c+1 >= i,
  // weight off-diag x2 (exact doubling), diag x1, duplicate-lower-lane x0.
  // Per-element chains identical; only the f32 sum order differs (invisible;
  // HW-validated identical absmax R7/R9).
  f2 s2p = sp(0.0f);
  #pragma unroll
  for (int i = 0; i < 8; ++i) {
    #pragma unroll
    for (int c = 0; c < 4; ++c) {
      if (2*c + 1 >= i) {
        f2 g = sp(EL(P, 0, i)) * P[0*4 + c];
        #pragma unroll
        for (int j = 1; j < 8; ++j)
          g = FMA2(sp(EL(P, j, i)), P[j*4 + c], g);
        f2 idv; idv.x = (2*c == i) ? 1.0f : 0.0f;
        idv.y = (2*c + 1 == i) ? 1.0f : 0.0f;
        f2 e = g - idv;
        f2 we;
        we.x = (2*c > i) ? (e.x + e.x) : ((2*c == i) ? e.x : 0.0f);
        we.y = (2*c + 1 == i) ? e.y : (e.y + e.y);
        s2p = FMA2(we, e, s2p);
      }
    }
  }
  float frob = sqrtf(s2p.x + s2p.y);

  // wave shuffle reduce (f64) -> LDS -> one atomic per 256-thread block
  double dv = (double)frob;
  #pragma unroll
  for (int off = 32; off > 0; off >>= 1)
    dv += __shfl_down(dv, off);

  __shared__ double part[4];
  const int lane = threadIdx.x & 63;
  const int wid  = threadIdx.x >> 6;
  if (lane == 0) part[wid] = dv;
  __syncthreads();
  if (threadIdx.x == 0) {
    double s = (part[0] + part[1]) + (part[2] + part[3]);
    atomicAdd(acc, s);
  }
}

__global__ void finalize_kernel(const double* __restrict__ acc,
                                float* __restrict__ out, int nmat)
{
  out[0] = (float)(acc[0] / (double)nmat);
}

extern "C" void kernel_launch(void* const* d_in, const int* in_sizes, int n_in,
                              void* d_out, int out_size, void* d_ws, size_t ws_size,
                              hipStream_t stream) {
  const float* in = (const float*)d_in[0];
  float* out = (float*)d_out;
  double* acc = (double*)d_ws;
  int nmat = in_sizes[0] / 64;   // 524288
  hipMemsetAsync(d_ws, 0, sizeof(double), stream);
  triality_kernel<<<nmat / 256, 256, 0, stream>>>(in, acc);
  finalize_kernel<<<1, 1, 0, stream>>>(acc, out, nmat);
}

// Round 5
// 248.101 us; speedup vs baseline: 1.0254x; 1.0254x over previous
//
#include <hip/hip_runtime.h>
#include <math.h>

// Non-explicit FP stays separate mul/add; explicit fma models the reference's
// contraction (XLA CPU AllowFPOpFusion::Fast). NUMERICS FROZEN SINCE R3:
// absmax 1.117587e-08. All structural changes are bit-identical per-element,
// HW-VALIDATED (identical absmax) across R7(R1)/R9(R3)/R10(R4):
//  - packed skew A (ap[28]): lower = exact IEEE negation of upper
//    ((-a)*w == -(a*w), folds into fma neg modifier), diag = +0; l1 skips
//    the diag +0 no-op add. Validated in R7's run.
//  - A2/A4 mirrors are BITWISE equal: term k of A2[j][i] is
//    (-A[k][j])*(-A[i][k]) == A[i][k]*A[k][j] exactly, same k-order; A4 same
//    argument over bitwise-symmetric A2. A6=A4*A2 NOT bitwise symmetric.
//  - U fold into P=U+V / Q=V-U per element: identical chains, no reorder.
//  - swap/updates restricted to LIVE Q column-pairs (lanes j<k hold dead L).
//  - gram upper+x2 weighting: bitwise-symmetric gram; only final f32 sum
//    order changes — established invisible.
// REGISTER STRATEGY (hard lessons R4/R6/R7/R9/R10):
//  - NO occupancy-forcing attribute: waves_per_eu(5) clamped to 48 VGPR and
//    spilled 1.2 GB (605us). (256,3)/(256,2) also spilled.
//  - Occupancy cliff ABOVE 128 VGPR (m69): 136-VGPR builds run at 10.5%
//    occupancy vs 18.5% at 128 — 126us vs 88us. STAY <=128.
//  - R10 falsified "gather temps caused +8 VGPR": in-place swap still 136.
//    The fix must shrink the DATA live-set. This build: aa[64] -> ap[28]
//    (A is skew; transient af rebuilt only for the A2 matmul; U reads
//    ±ap broadcasts). Peak phases drop 256 -> 220 live floats.
#pragma clang fp contract(off)

typedef float f2 __attribute__((ext_vector_type(2)));

static __device__ __forceinline__ f2 sp(float x) { f2 r; r.x = x; r.y = x; return r; }
static __device__ __forceinline__ f2 sel2(bool d, f2 a, f2 b) {
  f2 r; r.x = d ? a.x : b.x; r.y = d ? a.y : b.y; return r;
}
#define FMA2(A, B, C) __builtin_elementwise_fma((A), (B), (C))

// element access into row-major f2-packed 8x8: m[i*4 + (j>>1)] lane (j&1)
#define EL(m, i, j) (m[(i)*4 + ((j) >> 1)][(j) & 1])

// strict-upper packed index (28 entries), i<j, compile-time after unroll
#define UA(i, j) ((((i) * (15 - (i))) / 2) + (j) - (i) - 1)
// skew A element from packed ap (negation folds into consumer's modifier)
#define ELA(i, k) ((i) < (k) ? ap[UA(i, k)] : ((i) > (k) ? -ap[UA(k, i)] : 0.0f))

// Full 8x8 matmul, fmaf k-chain, f2-paired over j. Used by the rare squaring
// path only. Bitwise == R5's scalar mm8 (full 8-term chains, first term mul).
__device__ __forceinline__ void mm8p(const f2* __restrict__ A,
                                     const f2* __restrict__ B,
                                     f2* __restrict__ C) {
  #pragma unroll
  for (int i = 0; i < 8; ++i) {
    #pragma unroll
    for (int c = 0; c < 4; ++c) {
      f2 s = sp(EL(A, i, 0)) * B[0*4 + c];
      #pragma unroll
      for (int k = 1; k < 8; ++k)
        s = FMA2(sp(EL(A, i, k)), B[k*4 + c], s);
      C[i*4 + c] = s;
    }
  }
}

// One thread per 8x8 block, 256-thread workgroups, NO min-waves bound:
// (256,1) leaves the allocator free. Data live-set peak is now ~220 floats
// (ap+a2+a4+w6 during A6; ap+w6+vv+uu during U) ~= 110 VGPRs + temps.
__global__ __launch_bounds__(256, 1)
void triality_kernel(const float* __restrict__ in, double* __restrict__ acc)
{
  const int t = blockIdx.x * 256 + threadIdx.x;
  const float4* src = (const float4*)(in + (size_t)t * 64);

  float p[64];
  #pragma unroll
  for (int i = 0; i < 16; ++i) {
    float4 q4 = src[i];
    p[4*i+0] = q4.x; p[4*i+1] = q4.y; p[4*i+2] = q4.z; p[4*i+3] = q4.w;
  }

  // packed strict-upper skew part: ap[UA(i,j)] = 0.5*(p_ij - p_ji), i<j.
  // Identical bits to the full-aa upper entries; lower were exact negations;
  // diag was +0 (validated R7).
  float ap[28];
  #pragma unroll
  for (int i = 0; i < 8; ++i)
    #pragma unroll
    for (int j = i + 1; j < 8; ++j)
      ap[UA(i, j)] = 0.5f * (p[i*8 + j] - p[j*8 + i]);

  // 1-norm: per column j, ascending i (diag +0 add was a no-op; |-x|==|x|),
  // then running max — identical op order to R5 (validated R7).
  float l1 = 0.0f;
  #pragma unroll
  for (int j = 0; j < 8; ++j) {
    float cs = 0.0f;
    #pragma unroll
    for (int i = 0; i < 8; ++i) {
      if (i < j)      cs = cs + fabsf(ap[UA(i, j)]);
      else if (i > j) cs = cs + fabsf(ap[UA(j, i)]);
    }
    l1 = fmaxf(l1, cs);
  }

  // n_squarings = max(0, floor(log2(A_L1 / 3.925724783138660)))
  float fl = floorf(log2f(l1 / 3.925724783138660f));
  int ns = (fl > 0.0f) ? (int)fl : 0;
  if (ns > 0) {
    float sc = exp2f((float)(-ns));   // exact power of two
    #pragma unroll
    for (int m = 0; m < 28; ++m) ap[m] = ap[m] * sc;   // (-u)*sc == -(u*sc)
  }

  // transient full skew A (f2 rows) — only the A2 matmul reads it; dies after.
  f2 af[32];
  #pragma unroll
  for (int i = 0; i < 8; ++i)
    #pragma unroll
    for (int j = 0; j < 8; ++j)
      EL(af, i, j) = (i < j) ? ap[UA(i, j)]
                   : ((i > j) ? -ap[UA(j, i)] : 0.0f);

  // A2 = A*A (bitwise symmetric): compute f2 pairs with 2c+1 >= i, mirror the
  // 12 fully-lower pairs (mirror bits proven equal, header; HW-validated).
  // Full 8-term fmaf chains, j-paired — chains identical to R5.
  f2 a2[32];
  #pragma unroll
  for (int i = 0; i < 8; ++i)
    #pragma unroll
    for (int c = 0; c < 4; ++c) {
      if (2*c + 1 >= i) {
        f2 s = sp(EL(af, i, 0)) * af[0*4 + c];
        #pragma unroll
        for (int k = 1; k < 8; ++k)
          s = FMA2(sp(EL(af, i, k)), af[k*4 + c], s);
        a2[i*4 + c] = s;
      }
    }
  #pragma unroll
  for (int i = 0; i < 8; ++i)
    #pragma unroll
    for (int c = 0; c < 4; ++c)
      if (2*c + 1 < i) {
        EL(a2, i, 2*c)     = EL(a2, 2*c,     i);
        EL(a2, i, 2*c + 1) = EL(a2, 2*c + 1, i);
      }

  // A4 = A2*A2 (bitwise symmetric, same argument over symmetric A2): compute
  // upper pairs, mirror the rest. Chains identical to R5/R6's full compute.
  f2 a4[32];
  #pragma unroll
  for (int i = 0; i < 8; ++i)
    #pragma unroll
    for (int c = 0; c < 4; ++c) {
      if (2*c + 1 >= i) {
        f2 s = sp(EL(a2, i, 0)) * a2[0*4 + c];
        #pragma unroll
        for (int k = 1; k < 8; ++k)
          s = FMA2(sp(EL(a2, i, k)), a2[k*4 + c], s);
        a4[i*4 + c] = s;
      }
    }
  #pragma unroll
  for (int i = 0; i < 8; ++i)
    #pragma unroll
    for (int c = 0; c < 4; ++c)
      if (2*c + 1 < i) {
        EL(a4, i, 2*c)     = EL(a4, 2*c,     i);
        EL(a4, i, 2*c + 1) = EL(a4, 2*c + 1, i);
      }

  // A6 = A4*A2 (full — not bitwise symmetric)
  f2 w6[32];
  #pragma unroll
  for (int i = 0; i < 8; ++i)
    #pragma unroll
    for (int c = 0; c < 4; ++c) {
      f2 s = sp(EL(a4, i, 0)) * a2[0*4 + c];
      #pragma unroll
      for (int k = 1; k < 8; ++k)
        s = FMA2(sp(EL(a4, i, k)), a2[k*4 + c], s);
      w6[i*4 + c] = s;
    }

  // XLA backend-fused polynomial combine (validated R3), j-paired, in place:
  //   W = fma(277200, A2, fma(1512, A4, A6)) + diag(8648640)   -> w6
  //   V = fma(1995840, A2, fma(56, A6, 25200*A4)) + diag(17297280) -> vv
  f2 vv[32];
  #pragma unroll
  for (int e = 0; e < 32; ++e) {
    f2 x6 = w6[e], x4 = a4[e], x2 = a2[e];
    f2 w = FMA2(sp(1512.0f), x4, x6);
    w = FMA2(sp(277200.0f), x2, w);
    f2 v = FMA2(sp(56.0f), x6, sp(25200.0f) * x4);
    v = FMA2(sp(1995840.0f), x2, v);
    w6[e] = w; vv[e] = v;
  }
  #pragma unroll
  for (int i = 0; i < 8; ++i) {   // diagonal adds (scalar halves)
    EL(w6, i, i) = EL(w6, i, i) + 8648640.0f;
    EL(vv, i, i) = EL(vv, i, i) + 17297280.0f;
  }

  // U = A @ W from packed ap broadcasts (k==i term is fma(+0,w,s)==s —
  // R5-equivalent; negation folds into the fma operand modifier), folded per
  // element into P = U + V and Q = V - U. Validated R7 (ELA U-loop) +
  // R9/R10 (fold). Chains identical.
  f2 uu[32];
  #pragma unroll
  for (int i = 0; i < 8; ++i)
    #pragma unroll
    for (int c = 0; c < 4; ++c) {
      f2 s = sp(ELA(i, 0)) * w6[0*4 + c];
      #pragma unroll
      for (int k = 1; k < 8; ++k)
        s = FMA2(sp(ELA(i, k)), w6[k*4 + c], s);
      f2 V = vv[i*4 + c];
      uu[i*4 + c] = s + V;   // P = U + V
      vv[i*4 + c] = V - s;   // Q = V - U
    }
  f2* P = uu;
  f2* Q = vv;

  // ---- fused augmented elimination on [Q|P]: getrf(Q) + laswp(P) +
  // unit-lower trsm, interleaved per step k (bit-identical to the separate
  // passes). Swap is IN-PLACE progressive (d true at most once), restricted
  // to LIVE Q column-pairs (c >= k>>1) + all P columns.
  #pragma unroll
  for (int k = 0; k < 8; ++k) {
    float amax = fabsf(EL(Q, k, k)); int jp = k;
    #pragma unroll
    for (int i = k + 1; i < 8; ++i) {
      float av = fabsf(EL(Q, i, k));
      if (av > amax) { amax = av; jp = i; }   // first max, like isamax
    }
    const int c0 = k >> 1;
    #pragma unroll
    for (int i = k + 1; i < 8; ++i) {
      bool d = (jp == i);
      #pragma unroll
      for (int c = c0; c < 4; ++c) {
        f2 qk = Q[k*4 + c], qi = Q[i*4 + c];
        Q[k*4 + c] = sel2(d, qi, qk);
        Q[i*4 + c] = sel2(d, qk, qi);
      }
      #pragma unroll
      for (int c = 0; c < 4; ++c) {
        f2 pk_ = P[k*4 + c], pi = P[i*4 + c];
        P[k*4 + c] = sel2(d, pi, pk_);
        P[i*4 + c] = sel2(d, pk_, pi);
      }
    }

    // pivot-column scale: direct IEEE divide (validated R3)
    float dk = EL(Q, k, k);
    #pragma unroll
    for (int i = k + 1; i < 8; ++i) EL(Q, i, k) = EL(Q, i, k) / dk;
    // trailing updates: Q as pk pairs over live columns (lik read first;
    // corrupted lanes j<=k are dead L storage) + P row-axpy (pk).
    #pragma unroll
    for (int i = k + 1; i < 8; ++i) {
      float lik = EL(Q, i, k);
      f2 nl = sp(-lik);
      #pragma unroll
      for (int c = c0; c < 4; ++c)
        Q[i*4 + c] = FMA2(nl, Q[k*4 + c], Q[i*4 + c]);
      #pragma unroll
      for (int c = 0; c < 4; ++c)
        P[i*4 + c] = FMA2(nl, P[k*4 + c], P[i*4 + c]);
    }
  }

  // strsm: non-unit upper, k descending, IEEE f32 divide per element
  #pragma unroll
  for (int k = 7; k >= 0; --k) {
    float dk = EL(Q, k, k);
    #pragma unroll
    for (int j = 0; j < 8; ++j) EL(P, k, j) = EL(P, k, j) / dk;
    #pragma unroll
    for (int i = 0; i < k; ++i) {
      f2 nu = sp(-EL(Q, i, k));
      #pragma unroll
      for (int c = 0; c < 4; ++c)
        P[i*4 + c] = FMA2(nu, P[k*4 + c], P[i*4 + c]);
    }
  }

  // repeated squaring (ns in {0,1} statistically)
  for (int sq = 0; sq < ns; ++sq) {
    f2 t2[32];
    mm8p(P, P, t2);
    #pragma unroll
    for (int e = 0; e < 32; ++e) P[e] = t2[e];
  }

  // gram = R^T R - I: bitwise symmetric -> compute pairs with 2c+1 >= i,
  // weight off-diag x2 (exact doubling), diag x1, duplicate-lower-lane x0.
  // Per-element chains identical; only the f32 sum order differs (invisible;
  // HW-validated R7/R9/R10).
  f2 s2p = sp(0.0f);
  #pragma unroll
  for (int i = 0; i < 8; ++i) {
    #pragma unroll
    for (int c = 0; c < 4; ++c) {
      if (2*c + 1 >= i) {
        f2 g = sp(EL(P, 0, i)) * P[0*4 + c];
        #pragma unroll
        for (int j = 1; j < 8; ++j)
          g = FMA2(sp(EL(P, j, i)), P[j*4 + c], g);
        f2 idv; idv.x = (2*c == i) ? 1.0f : 0.0f;
        idv.y = (2*c + 1 == i) ? 1.0f : 0.0f;
        f2 e = g - idv;
        f2 we;
        we.x = (2*c > i) ? (e.x + e.x) : ((2*c == i) ? e.x : 0.0f);
        we.y = (2*c + 1 == i) ? e.y : (e.y + e.y);
        s2p = FMA2(we, e, s2p);
      }
    }
  }
  float frob = sqrtf(s2p.x + s2p.y);

  // wave shuffle reduce (f64) -> LDS -> one atomic per 256-thread block
  double dv = (double)frob;
  #pragma unroll
  for (int off = 32; off > 0; off >>= 1)
    dv += __shfl_down(dv, off);

  __shared__ double part[4];
  const int lane = threadIdx.x & 63;
  const int wid  = threadIdx.x >> 6;
  if (lane == 0) part[wid] = dv;
  __syncthreads();
  if (threadIdx.x == 0) {
    double s = (part[0] + part[1]) + (part[2] + part[3]);
    atomicAdd(acc, s);
  }
}

__global__ void finalize_kernel(const double* __restrict__ acc,
                                float* __restrict__ out, int nmat)
{
  out[0] = (float)(acc[0] / (double)nmat);
}

extern "C" void kernel_launch(void* const* d_in, const int* in_sizes, int n_in,
                              void* d_out, int out_size, void* d_ws, size_t ws_size,
                              hipStream_t stream) {
  const float* in = (const float*)d_in[0];
  float* out = (float*)d_out;
  double* acc = (double*)d_ws;
  int nmat = in_sizes[0] / 64;   // 524288
  hipMemsetAsync(d_ws, 0, sizeof(double), stream);
  triality_kernel<<<nmat / 256, 256, 0, stream>>>(in, acc);
  finalize_kernel<<<1, 1, 0, stream>>>(acc, out, nmat);
}